// Round 1
// baseline (13226.308 us; speedup 1.0000x reference)
//
#include <hip/hip_runtime.h>

// ---------------------------------------------------------------------------
// TranslatorEncoderRNN: bidirectional masked LSTM encoder.
// B=64, T=512, E=512, H=512 (per dir), V=32000, PAD=0.
// Outputs (flat in d_out): output (B,T,1024) f32 | ht (B,1024) | ct (B,1024) | mask (B,T)
// ---------------------------------------------------------------------------

#define Bn 64
#define Tn 512
#define En 512
#define Hn 512
#define NG 2048            // 4*H gate columns
#define KK 1024            // E + H fused K
#define NWG 64             // recurrent workgroups (32 per direction)

#define OUT_HT  33554432u  // B*T*2H
#define OUT_CT  33619968u
#define OUT_MSK 33685504u

typedef __bf16 v8bf __attribute__((ext_vector_type(8)));
typedef float  v4f  __attribute__((ext_vector_type(4)));

__device__ __forceinline__ unsigned short f2bf(float f) {
    unsigned u = __float_as_uint(f);
    u = (u + 0x7FFFu + ((u >> 16) & 1u)) >> 16;   // round-to-nearest-even
    return (unsigned short)u;
}

__device__ __forceinline__ v8bf ldfrag(const unsigned short* p) {
    return *reinterpret_cast<const v8bf*>(p);
}

__device__ __forceinline__ float fsig(float x) {
    return 1.0f / (1.0f + __expf(-x));
}
__device__ __forceinline__ float ftanh(float x) {
    x = fminf(fmaxf(x, -15.0f), 15.0f);
    float e = __expf(2.0f * x);
    return (e - 1.0f) / (e + 1.0f);
}

// --------------------------- prep kernels ----------------------------------

// weights: Wcat[dir][n][k], k<512 from Wih[n][k], k>=512 from Whh[n][k-512], bf16
__global__ void k_weights(const float* __restrict__ Wih_f, const float* __restrict__ Whh_f,
                          const float* __restrict__ Wih_b, const float* __restrict__ Whh_b,
                          unsigned short* __restrict__ Wcat) {
    int idx = blockIdx.x * 256 + threadIdx.x;       // one per 4 elements
    if (idx >= 2 * NG * (KK / 4)) return;
    int k4 = idx & 255;
    int n  = (idx >> 8) & 2047;
    int d  = idx >> 19;
    int k  = k4 * 4;
    const float* src;
    if (k < 512) src = (d ? Wih_b : Wih_f) + (size_t)n * 512 + k;
    else         src = (d ? Whh_b : Whh_f) + (size_t)n * 512 + (k - 512);
    float4 v = *(const float4*)src;
    unsigned short o[4] = { f2bf(v.x), f2bf(v.y), f2bf(v.z), f2bf(v.w) };
    *(ushort4*)(Wcat + (size_t)idx * 4) = *(const ushort4*)o;
}

__global__ void k_bias(const float* __restrict__ bihf, const float* __restrict__ bhhf,
                       const float* __restrict__ bihb, const float* __restrict__ bhhb,
                       float* __restrict__ bias) {
    int i = blockIdx.x * 256 + threadIdx.x;
    if (i >= 2 * NG) return;
    int d = i >> 11, n = i & 2047;
    bias[i] = d ? (bihb[n] + bhhb[n]) : (bihf[n] + bhhf[n]);
}

// zero h_pub (2 dirs x 2 phases x 64 x 512 bf16) and the barrier counter
__global__ void k_zero(unsigned short* __restrict__ h_pub, unsigned* __restrict__ cnt) {
    int i = blockIdx.x * 256 + threadIdx.x;
    if (i == 0) *cnt = 0u;
    if (i < (2 * 2 * Bn * Hn) / 8) {
        uint4 z = {0u, 0u, 0u, 0u};
        ((uint4*)h_pub)[i] = z;
    }
}

// embedding gather -> x[t][b][e] bf16, with table row PAD(=0) zeroed
__global__ void k_embed(const int* __restrict__ inputs, const float* __restrict__ table,
                        unsigned short* __restrict__ x) {
    int idx = blockIdx.x * 256 + threadIdx.x;       // (t*64+b)*64 + e8
    if (idx >= Tn * Bn * (En / 8)) return;
    int e8 = idx & 63;
    int b  = (idx >> 6) & 63;
    int t  = idx >> 12;
    int tok = inputs[b * Tn + t];
    unsigned short o[8] = {0, 0, 0, 0, 0, 0, 0, 0};
    if (tok != 0) {
        const float* src = table + (size_t)tok * En + e8 * 8;
        float4 v0 = ((const float4*)src)[0];
        float4 v1 = ((const float4*)src)[1];
        o[0] = f2bf(v0.x); o[1] = f2bf(v0.y); o[2] = f2bf(v0.z); o[3] = f2bf(v0.w);
        o[4] = f2bf(v1.x); o[5] = f2bf(v1.y); o[6] = f2bf(v1.z); o[7] = f2bf(v1.w);
    }
    unsigned short* dst = x + (size_t)idx * 8;
    ((ushort4*)dst)[0] = *(const ushort4*)(o);
    ((ushort4*)dst)[1] = *(const ushort4*)(o + 4);
}

__global__ void k_mask(const int* __restrict__ lengths, float* __restrict__ mask_out) {
    int i = blockIdx.x * 256 + threadIdx.x;
    if (i >= Bn * Tn) return;
    int b = i >> 9, t = i & 511;
    mask_out[i] = (t < lengths[b]) ? 1.0f : 0.0f;
}

// --------------------------- recurrent kernel ------------------------------
// 64 WGs x 256 threads, persistent across all 512 time steps.
// WG wg: dir = wg>>5, owns h-columns [hc0, hc0+16). Computes gate columns
// {g*512 + hc0 + j : g in 0..3, j in 0..15} (reordered as 4 N-tiles of 16).
// Per step: gates = [x_t | h] @ W_slice^T via MFMA (M=64,N=64,K=1024),
// fragments streamed from global (L2-resident weights), LSTM elementwise,
// publish bf16 h (double buffered), device-scope atomic barrier.

__global__ __launch_bounds__(256) void lstm_recur(
    const unsigned short* __restrict__ x,       // [T][B][E] bf16
    const unsigned short* __restrict__ Wcat,    // [2][2048][1024] bf16
    unsigned short* __restrict__ h_pub,         // [2][2][B][H] bf16
    const float* __restrict__ bias,             // [2][2048]
    const int* __restrict__ lengths,            // [B]
    float* __restrict__ out,                    // d_out
    unsigned* __restrict__ cnt)
{
    const int wg   = blockIdx.x;
    const int dir  = wg >> 5;
    const int hc0  = (wg & 31) * 16;
    const int tid  = threadIdx.x;
    const int lane = tid & 63;
    const int wave = tid >> 6;
    const int wm   = wave >> 1;
    const int wn   = wave & 1;
    const int l15  = lane & 15;
    const int kq   = lane >> 4;

    __shared__ float gLds[64][65];
    __shared__ float hS[64][16];
    __shared__ float cS[64][16];
    __shared__ int   lenS[64];

    for (int i = tid; i < 64 * 16; i += 256) { hS[i >> 4][i & 15] = 0.0f; cS[i >> 4][i & 15] = 0.0f; }
    if (tid < 64) lenS[tid] = lengths[tid];
    __syncthreads();

    const unsigned short* Wd = Wcat + (size_t)dir * (NG * KK);
    unsigned short* hp = h_pub + (size_t)dir * (2 * Bn * Hn);
    const float* bs = bias + dir * NG;

    const int rowA0 = 32 * wm + l15;
    const int rowA1 = rowA0 + 16;
    const int n0 = (2 * wn + 0) * 512 + hc0 + l15;
    const int n1 = (2 * wn + 1) * 512 + hc0 + l15;
    const unsigned short* pB0 = Wd + (size_t)n0 * KK + kq * 8;
    const unsigned short* pB1 = Wd + (size_t)n1 * KK + kq * 8;

    for (int s = 0; s < Tn; ++s) {
        const int t  = dir ? (Tn - 1 - s) : s;
        const int ph = s & 1;
        const unsigned short* hpr = hp + ph * (Bn * Hn);
        const unsigned short* xt  = x + (size_t)t * (Bn * En);

        v4f a00 = {0, 0, 0, 0}, a01 = {0, 0, 0, 0}, a10 = {0, 0, 0, 0}, a11 = {0, 0, 0, 0};

        const unsigned short* pA0 = xt + rowA0 * En + kq * 8;
        const unsigned short* pA1 = xt + rowA1 * En + kq * 8;
        #pragma unroll 4
        for (int ks = 0; ks < 16; ++ks) {                 // k = 0..511 (x part)
            v8bf fa0 = ldfrag(pA0 + ks * 32);
            v8bf fa1 = ldfrag(pA1 + ks * 32);
            v8bf fb0 = ldfrag(pB0 + ks * 32);
            v8bf fb1 = ldfrag(pB1 + ks * 32);
            a00 = __builtin_amdgcn_mfma_f32_16x16x32_bf16(fa0, fb0, a00, 0, 0, 0);
            a01 = __builtin_amdgcn_mfma_f32_16x16x32_bf16(fa0, fb1, a01, 0, 0, 0);
            a10 = __builtin_amdgcn_mfma_f32_16x16x32_bf16(fa1, fb0, a10, 0, 0, 0);
            a11 = __builtin_amdgcn_mfma_f32_16x16x32_bf16(fa1, fb1, a11, 0, 0, 0);
        }
        const unsigned short* pH0 = hpr + rowA0 * Hn + kq * 8;
        const unsigned short* pH1 = hpr + rowA1 * Hn + kq * 8;
        #pragma unroll 4
        for (int ks = 0; ks < 16; ++ks) {                 // k = 512..1023 (h part)
            v8bf fa0 = ldfrag(pH0 + ks * 32);
            v8bf fa1 = ldfrag(pH1 + ks * 32);
            v8bf fb0 = ldfrag(pB0 + (16 + ks) * 32);
            v8bf fb1 = ldfrag(pB1 + (16 + ks) * 32);
            a00 = __builtin_amdgcn_mfma_f32_16x16x32_bf16(fa0, fb0, a00, 0, 0, 0);
            a01 = __builtin_amdgcn_mfma_f32_16x16x32_bf16(fa0, fb1, a01, 0, 0, 0);
            a10 = __builtin_amdgcn_mfma_f32_16x16x32_bf16(fa1, fb0, a10, 0, 0, 0);
            a11 = __builtin_amdgcn_mfma_f32_16x16x32_bf16(fa1, fb1, a11, 0, 0, 0);
        }

        // gates -> LDS. C/D layout: col = lane&15, row = (lane>>4)*4 + reg.
        {
            int c0 = 32 * wn + l15;
            int r  = 32 * wm + kq * 4;
            #pragma unroll
            for (int q = 0; q < 4; ++q) {
                gLds[r + q][c0     ] = a00[q];
                gLds[r + q][c0 + 16] = a01[q];
                gLds[r + 16 + q][c0     ] = a10[q];
                gLds[r + 16 + q][c0 + 16] = a11[q];
            }
        }
        __syncthreads();

        // elementwise LSTM for this WG's 16 h-columns x 64 batches
        for (int p = tid; p < 1024; p += 256) {
            int b = p >> 4, j = p & 15;
            float gi = gLds[b][ 0 + j] + bs[        hc0 + j];
            float gf = gLds[b][16 + j] + bs[ 512 +  hc0 + j];
            float gg = gLds[b][32 + j] + bs[1024 +  hc0 + j];
            float go = gLds[b][48 + j] + bs[1536 +  hc0 + j];
            float i_ = fsig(gi), f_ = fsig(gf), o_ = fsig(go), g_ = ftanh(gg);
            float c_old = cS[b][j], h_old = hS[b][j];
            float c_new = fmaf(f_, c_old, i_ * g_);
            float h_new = o_ * ftanh(c_new);
            if (t >= lenS[b]) { c_new = c_old; h_new = h_old; }
            cS[b][j] = c_new;
            hS[b][j] = h_new;
            hp[(ph ^ 1) * (Bn * Hn) + b * Hn + hc0 + j] = f2bf(h_new);
            out[((size_t)b * Tn + t) * 1024 + (size_t)dir * 512 + hc0 + j] = h_new;
            if (s == Tn - 1) {
                out[OUT_HT + (size_t)b * 1024 + dir * 512 + hc0 + j] = h_new;
                out[OUT_CT + (size_t)b * 1024 + dir * 512 + hc0 + j] = c_new;
            }
        }

        // device-scope barrier (monotonic counter, release/acquire)
        if (s < Tn - 1) {
            __threadfence();
            __syncthreads();
            if (tid == 0) {
                __hip_atomic_fetch_add(cnt, 1u, __ATOMIC_RELEASE, __HIP_MEMORY_SCOPE_AGENT);
                unsigned tgt = (unsigned)NWG * (unsigned)(s + 1);
                while (__hip_atomic_load(cnt, __ATOMIC_RELAXED, __HIP_MEMORY_SCOPE_AGENT) < tgt) {
                    __builtin_amdgcn_s_sleep(1);
                }
            }
            __syncthreads();
            unsigned v = __hip_atomic_load(cnt, __ATOMIC_ACQUIRE, __HIP_MEMORY_SCOPE_AGENT);
            asm volatile("" :: "v"(v));     // keep the acquire load alive
        }
    }
}

// --------------------------- launcher --------------------------------------

extern "C" void kernel_launch(void* const* d_in, const int* in_sizes, int n_in,
                              void* d_out, int out_size, void* d_ws, size_t ws_size,
                              hipStream_t stream) {
    (void)in_sizes; (void)n_in; (void)out_size; (void)ws_size;

    const int*   inputs  = (const int*)d_in[0];
    const int*   lengths = (const int*)d_in[1];
    const float* table   = (const float*)d_in[2];
    const float* Wih_f   = (const float*)d_in[3];
    const float* Whh_f   = (const float*)d_in[4];
    const float* bih_f   = (const float*)d_in[5];
    const float* bhh_f   = (const float*)d_in[6];
    const float* Wih_b   = (const float*)d_in[7];
    const float* Whh_b   = (const float*)d_in[8];
    const float* bih_b   = (const float*)d_in[9];
    const float* bhh_b   = (const float*)d_in[10];
    float* out = (float*)d_out;

    char* w = (char*)d_ws;
    unsigned short* x     = (unsigned short*)(w);                         // 32 MB
    unsigned short* Wcat  = (unsigned short*)(w + 33554432);              // 8 MB
    unsigned short* h_pub = (unsigned short*)(w + 41943040);              // 256 KB
    float*          bias  = (float*)(w + 42205184);                       // 16 KB
    unsigned*       cnt   = (unsigned*)(w + 42221568);                    // 4 B

    k_weights<<<4096, 256, 0, stream>>>(Wih_f, Whh_f, Wih_b, Whh_b, Wcat);
    k_bias<<<16, 256, 0, stream>>>(bih_f, bhh_f, bih_b, bhh_b, bias);
    k_zero<<<128, 256, 0, stream>>>(h_pub, cnt);
    k_embed<<<8192, 256, 0, stream>>>(inputs, table, x);
    k_mask<<<128, 256, 0, stream>>>(lengths, out + OUT_MSK);
    lstm_recur<<<NWG, 256, 0, stream>>>(x, Wcat, h_pub, bias, lengths, out, cnt);
}

// Round 2
// 4859.700 us; speedup vs baseline: 2.7216x; 2.7216x over previous
//
#include <hip/hip_runtime.h>

// ---------------------------------------------------------------------------
// TranslatorEncoderRNN: bidirectional masked LSTM encoder.
// B=64, T=512, E=512, H=512 (per dir), V=32000, PAD=0.
// Outputs (flat in d_out): output (B,T,1024) f32 | ht (B,1024) | ct (B,1024) | mask (B,T)
//
// R2: no cache-wide fences. Whh in registers, Wih streamed from L2,
// h exchanged via sc0/sc1 coherent loads/stores + per-WG flag barrier.
// ---------------------------------------------------------------------------

#define Bn 64
#define Tn 512
#define En 512
#define Hn 512
#define NG 2048            // 4*H gate columns
#define KK 1024            // E + H fused K
#define NWG 64             // recurrent workgroups (32 per direction)

#define OUT_HT  33554432u  // B*T*2H
#define OUT_CT  33619968u
#define OUT_MSK 33685504u

typedef __bf16 v8bf __attribute__((ext_vector_type(8)));
typedef float  v4f  __attribute__((ext_vector_type(4)));
typedef unsigned v4u __attribute__((ext_vector_type(4)));
typedef unsigned v2u __attribute__((ext_vector_type(2)));

__device__ __forceinline__ unsigned short f2bf(float f) {
    unsigned u = __float_as_uint(f);
    u = (u + 0x7FFFu + ((u >> 16) & 1u)) >> 16;   // round-to-nearest-even
    return (unsigned short)u;
}

__device__ __forceinline__ v8bf ldfrag(const unsigned short* p) {
    return *reinterpret_cast<const v8bf*>(p);
}

// system-coherent 16B load (bypasses L1/L2 -> coherence point)
__device__ __forceinline__ v4u ld_co16(const unsigned short* p) {
    v4u r;
    asm volatile("global_load_dwordx4 %0, %1, off sc0 sc1" : "=v"(r) : "v"(p));
    return r;
}

__device__ __forceinline__ float fsig(float x) {
    return 1.0f / (1.0f + __expf(-x));
}
__device__ __forceinline__ float ftanh(float x) {
    x = fminf(fmaxf(x, -15.0f), 15.0f);
    float e = __expf(2.0f * x);
    return (e - 1.0f) / (e + 1.0f);
}

// --------------------------- prep kernels ----------------------------------

__global__ void k_weights(const float* __restrict__ Wih_f, const float* __restrict__ Whh_f,
                          const float* __restrict__ Wih_b, const float* __restrict__ Whh_b,
                          unsigned short* __restrict__ Wcat) {
    int idx = blockIdx.x * 256 + threadIdx.x;       // one per 4 elements
    if (idx >= 2 * NG * (KK / 4)) return;
    int k4 = idx & 255;
    int n  = (idx >> 8) & 2047;
    int d  = idx >> 19;
    int k  = k4 * 4;
    const float* src;
    if (k < 512) src = (d ? Wih_b : Wih_f) + (size_t)n * 512 + k;
    else         src = (d ? Whh_b : Whh_f) + (size_t)n * 512 + (k - 512);
    float4 v = *(const float4*)src;
    unsigned short o[4] = { f2bf(v.x), f2bf(v.y), f2bf(v.z), f2bf(v.w) };
    *(ushort4*)(Wcat + (size_t)idx * 4) = *(const ushort4*)o;
}

__global__ void k_bias(const float* __restrict__ bihf, const float* __restrict__ bhhf,
                       const float* __restrict__ bihb, const float* __restrict__ bhhb,
                       float* __restrict__ bias) {
    int i = blockIdx.x * 256 + threadIdx.x;
    if (i >= 2 * NG) return;
    int d = i >> 11, n = i & 2047;
    bias[i] = d ? (bihb[n] + bhhb[n]) : (bihf[n] + bhhf[n]);
}

// zero h_pub (2 dirs x 2 phases x 64 x 512 bf16) and the flag array
__global__ void k_zero(unsigned short* __restrict__ h_pub, unsigned* __restrict__ flags) {
    int i = blockIdx.x * 256 + threadIdx.x;
    if (i < NWG * 32) flags[i] = 0u;
    if (i < (2 * 2 * Bn * Hn) / 8) {
        uint4 z = {0u, 0u, 0u, 0u};
        ((uint4*)h_pub)[i] = z;
    }
}

// embedding gather -> x[t][b][e] bf16, with table row PAD(=0) zeroed
__global__ void k_embed(const int* __restrict__ inputs, const float* __restrict__ table,
                        unsigned short* __restrict__ x) {
    int idx = blockIdx.x * 256 + threadIdx.x;       // (t*64+b)*64 + e8
    if (idx >= Tn * Bn * (En / 8)) return;
    int e8 = idx & 63;
    int b  = (idx >> 6) & 63;
    int t  = idx >> 12;
    int tok = inputs[b * Tn + t];
    unsigned short o[8] = {0, 0, 0, 0, 0, 0, 0, 0};
    if (tok != 0) {
        const float* src = table + (size_t)tok * En + e8 * 8;
        float4 v0 = ((const float4*)src)[0];
        float4 v1 = ((const float4*)src)[1];
        o[0] = f2bf(v0.x); o[1] = f2bf(v0.y); o[2] = f2bf(v0.z); o[3] = f2bf(v0.w);
        o[4] = f2bf(v1.x); o[5] = f2bf(v1.y); o[6] = f2bf(v1.z); o[7] = f2bf(v1.w);
    }
    unsigned short* dst = x + (size_t)idx * 8;
    ((ushort4*)dst)[0] = *(const ushort4*)(o);
    ((ushort4*)dst)[1] = *(const ushort4*)(o + 4);
}

__global__ void k_mask(const int* __restrict__ lengths, float* __restrict__ mask_out) {
    int i = blockIdx.x * 256 + threadIdx.x;
    if (i >= Bn * Tn) return;
    int b = i >> 9, t = i & 511;
    mask_out[i] = (t < lengths[b]) ? 1.0f : 0.0f;
}

// --------------------------- recurrent kernel ------------------------------
// 64 WGs x 256 threads, persistent. WG wg: dir = wg>>5, owns h-cols
// [hc0,hc0+16). Per step: gates = [x_t | h] @ W_slice^T (M=64,N=64,K=1024).
// x-part: A and B streamed from L2 (plain loads). h-part: Whh in registers,
// h(t-1) staged into swizzled LDS via coherent loads. Publish h coherent,
// per-WG flag barrier (no RMW, no cache-wide fences).

__global__ __launch_bounds__(256, 1) void lstm_recur(
    const unsigned short* __restrict__ x,       // [T][B][E] bf16
    const unsigned short* __restrict__ Wcat,    // [2][2048][1024] bf16
    unsigned short* __restrict__ h_pub,         // [2][2][B][H] bf16
    const float* __restrict__ bias,             // [2][2048]
    const int* __restrict__ lengths,            // [B]
    float* __restrict__ out,                    // d_out
    unsigned* __restrict__ flags)               // [NWG][32] cacheline-padded
{
    const int wg   = blockIdx.x;
    const int dir  = wg >> 5;
    const int hc0  = (wg & 31) * 16;
    const int tid  = threadIdx.x;
    const int lane = tid & 63;
    const int wave = tid >> 6;
    const int wm   = wave >> 1;
    const int wn   = wave & 1;
    const int l15  = lane & 15;
    const int kq   = lane >> 4;

    __shared__ unsigned short hA[64 * 512];     // 64 KB, swizzled h tile
    __shared__ float gLds[64][65];
    __shared__ float hS[64][17];
    __shared__ float cS[64][17];
    __shared__ int   lenS[64];

    // init LDS state
    {
        int b = tid >> 2, jg = tid & 3;
        #pragma unroll
        for (int jj = 0; jj < 4; ++jj) { hS[b][jg * 4 + jj] = 0.0f; cS[b][jg * 4 + jj] = 0.0f; }
        if (tid < 64) lenS[tid] = lengths[tid];
    }

    const unsigned short* Wd = Wcat + (size_t)dir * (NG * KK);
    unsigned short* hp = h_pub + (size_t)dir * (2 * Bn * Hn);
    const float* bs = bias + dir * NG;

    const int rowA0 = 32 * wm + l15;
    const int rowA1 = rowA0 + 16;
    const int n0 = (2 * wn + 0) * 512 + hc0 + l15;
    const int n1 = (2 * wn + 1) * 512 + hc0 + l15;
    const unsigned short* pB0 = Wd + (size_t)n0 * KK + kq * 8;
    const unsigned short* pB1 = Wd + (size_t)n1 * KK + kq * 8;

    // per-thread bias registers (b = tid>>2, j = (tid&3)*4 + jj)
    const int eb = tid >> 2, ejg = tid & 3;
    float bI[4], bF[4], bG[4], bO[4];
    #pragma unroll
    for (int jj = 0; jj < 4; ++jj) {
        int j = hc0 + ejg * 4 + jj;
        bI[jj] = bs[j]; bF[jj] = bs[512 + j]; bG[jj] = bs[1024 + j]; bO[jj] = bs[1536 + j];
    }

    // preload Whh fragments (K = 512..1023) into registers: 128 VGPRs
    v8bf whB0[16], whB1[16];
    #pragma unroll
    for (int ks = 0; ks < 16; ++ks) {
        whB0[ks] = ldfrag(pB0 + (16 + ks) * 32);
        whB1[ks] = ldfrag(pB1 + (16 + ks) * 32);
    }

    // LDS A-frag addressing (swizzled): el = row*512 + ((kq*8 + ks*32) ^ ((row&7)<<3))
    const unsigned short* lA0 = hA + rowA0 * 512;
    const unsigned short* lA1 = hA + rowA1 * 512;
    const int swA0 = (rowA0 & 7) << 3;
    const int swA1 = (rowA1 & 7) << 3;

    __syncthreads();

    for (int s = 0; s < Tn; ++s) {
        const int t  = dir ? (Tn - 1 - s) : s;
        const int ph = s & 1;

        // ---- barrier: wait for all peers of my direction to publish step s's h
        if (s > 0) {
            if (wave == 0) {
                unsigned* fp = flags + (dir * 32 + (lane & 31)) * 32;
                while (__hip_atomic_load(fp, __ATOMIC_RELAXED, __HIP_MEMORY_SCOPE_AGENT) < (unsigned)s)
                    __builtin_amdgcn_s_sleep(1);
            }
            __syncthreads();
        }

        v4f a00 = {0, 0, 0, 0}, a01 = {0, 0, 0, 0}, a10 = {0, 0, 0, 0}, a11 = {0, 0, 0, 0};

        // ---- x-part: K = 0..511, A (x_t) + B (Wih) streamed from L2
        {
            const unsigned short* xt = x + (size_t)t * (Bn * En);
            const unsigned short* pA0 = xt + rowA0 * En + kq * 8;
            const unsigned short* pA1 = xt + rowA1 * En + kq * 8;
            #pragma unroll
            for (int ks = 0; ks < 16; ++ks) {
                v8bf fa0 = ldfrag(pA0 + ks * 32);
                v8bf fa1 = ldfrag(pA1 + ks * 32);
                v8bf fb0 = ldfrag(pB0 + ks * 32);
                v8bf fb1 = ldfrag(pB1 + ks * 32);
                a00 = __builtin_amdgcn_mfma_f32_16x16x32_bf16(fa0, fb0, a00, 0, 0, 0);
                a01 = __builtin_amdgcn_mfma_f32_16x16x32_bf16(fa0, fb1, a01, 0, 0, 0);
                a10 = __builtin_amdgcn_mfma_f32_16x16x32_bf16(fa1, fb0, a10, 0, 0, 0);
                a11 = __builtin_amdgcn_mfma_f32_16x16x32_bf16(fa1, fb1, a11, 0, 0, 0);
            }
        }

        // ---- stage h(t-1) into swizzled LDS via coherent loads
        {
            const unsigned short* hpr = hp + ph * (Bn * Hn);
            v4u tmp[16];
            #pragma unroll
            for (int i2 = 0; i2 < 16; ++i2) {
                tmp[i2] = ld_co16(hpr + (size_t)(i2 * 256 + tid) * 8);
            }
            asm volatile("s_waitcnt vmcnt(0)" ::: "memory");
            #pragma unroll
            for (int i2 = 0; i2 < 16; ++i2) {
                int id = i2 * 256 + tid;
                int row = id >> 6, c16 = id & 63;
                *(v4u*)&hA[row * 512 + ((c16 * 8) ^ ((row & 7) << 3))] = tmp[i2];
            }
        }
        __syncthreads();

        // ---- h-part: K = 512..1023, A from LDS, B from registers
        #pragma unroll
        for (int ks = 0; ks < 16; ++ks) {
            v8bf fa0 = *(const v8bf*)&lA0[(kq * 8 + ks * 32) ^ swA0];
            v8bf fa1 = *(const v8bf*)&lA1[(kq * 8 + ks * 32) ^ swA1];
            a00 = __builtin_amdgcn_mfma_f32_16x16x32_bf16(fa0, whB0[ks], a00, 0, 0, 0);
            a01 = __builtin_amdgcn_mfma_f32_16x16x32_bf16(fa0, whB1[ks], a01, 0, 0, 0);
            a10 = __builtin_amdgcn_mfma_f32_16x16x32_bf16(fa1, whB0[ks], a10, 0, 0, 0);
            a11 = __builtin_amdgcn_mfma_f32_16x16x32_bf16(fa1, whB1[ks], a11, 0, 0, 0);
        }

        // ---- gates -> LDS. C/D layout: col = lane&15, row = (lane>>4)*4 + reg.
        {
            int c0 = 32 * wn + l15;
            int r  = 32 * wm + kq * 4;
            #pragma unroll
            for (int q = 0; q < 4; ++q) {
                gLds[r + q][c0     ] = a00[q];
                gLds[r + q][c0 + 16] = a01[q];
                gLds[r + 16 + q][c0     ] = a10[q];
                gLds[r + 16 + q][c0 + 16] = a11[q];
            }
        }
        __syncthreads();

        // ---- elementwise LSTM: thread handles (b = tid>>2, j = (tid&3)*4 + 0..3)
        {
            const int b = eb, jg = ejg;
            float hn[4], cn[4];
            const int msk = (t < lenS[b]);
            #pragma unroll
            for (int jj = 0; jj < 4; ++jj) {
                int j = jg * 4 + jj;
                float gi = gLds[b][j]      + bI[jj];
                float gf = gLds[b][16 + j] + bF[jj];
                float gg = gLds[b][32 + j] + bG[jj];
                float go = gLds[b][48 + j] + bO[jj];
                float i_ = fsig(gi), f_ = fsig(gf), o_ = fsig(go), g_ = ftanh(gg);
                float c_old = cS[b][j], h_old = hS[b][j];
                float c_new = fmaf(f_, c_old, i_ * g_);
                float h_new = o_ * ftanh(c_new);
                if (!msk) { c_new = c_old; h_new = h_old; }
                cS[b][j] = c_new;
                hS[b][j] = h_new;
                hn[jj] = h_new; cn[jj] = c_new;
            }
            // output slice (coalesced 16B per thread)
            v4f ov = {hn[0], hn[1], hn[2], hn[3]};
            *(v4f*)&out[((size_t)b * Tn + t) * 1024 + (size_t)dir * 512 + hc0 + jg * 4] = ov;
            if (s == Tn - 1) {
                v4f cv = {cn[0], cn[1], cn[2], cn[3]};
                *(v4f*)&out[OUT_HT + (size_t)b * 1024 + dir * 512 + hc0 + jg * 4] = ov;
                *(v4f*)&out[OUT_CT + (size_t)b * 1024 + dir * 512 + hc0 + jg * 4] = cv;
            } else {
                // publish h (coherent 8B write-through)
                unsigned short q0 = f2bf(hn[0]), q1 = f2bf(hn[1]), q2 = f2bf(hn[2]), q3 = f2bf(hn[3]);
                v2u pk = { (unsigned)q0 | ((unsigned)q1 << 16), (unsigned)q2 | ((unsigned)q3 << 16) };
                const unsigned short* dst = hp + (ph ^ 1) * (Bn * Hn) + b * Hn + hc0 + jg * 4;
                asm volatile("global_store_dwordx2 %0, %1, off sc0 sc1" :: "v"(dst), "v"(pk) : "memory");
            }
        }

        // ---- signal: my h for step s+1 is visible
        if (s < Tn - 1) {
            asm volatile("s_waitcnt vmcnt(0)" ::: "memory");
            __syncthreads();
            if (tid == 0)
                __hip_atomic_store(flags + wg * 32, (unsigned)(s + 1), __ATOMIC_RELAXED, __HIP_MEMORY_SCOPE_AGENT);
        }
    }
}

// --------------------------- launcher --------------------------------------

extern "C" void kernel_launch(void* const* d_in, const int* in_sizes, int n_in,
                              void* d_out, int out_size, void* d_ws, size_t ws_size,
                              hipStream_t stream) {
    (void)in_sizes; (void)n_in; (void)out_size; (void)ws_size;

    const int*   inputs  = (const int*)d_in[0];
    const int*   lengths = (const int*)d_in[1];
    const float* table   = (const float*)d_in[2];
    const float* Wih_f   = (const float*)d_in[3];
    const float* Whh_f   = (const float*)d_in[4];
    const float* bih_f   = (const float*)d_in[5];
    const float* bhh_f   = (const float*)d_in[6];
    const float* Wih_b   = (const float*)d_in[7];
    const float* Whh_b   = (const float*)d_in[8];
    const float* bih_b   = (const float*)d_in[9];
    const float* bhh_b   = (const float*)d_in[10];
    float* out = (float*)d_out;

    char* w = (char*)d_ws;
    unsigned short* x     = (unsigned short*)(w);                         // 32 MB
    unsigned short* Wcat  = (unsigned short*)(w + 33554432);              // 8 MB
    unsigned short* h_pub = (unsigned short*)(w + 41943040);              // 256 KB
    float*          bias  = (float*)(w + 42205184);                       // 16 KB
    unsigned*       flags = (unsigned*)(w + 42221568);                    // 8 KB

    k_weights<<<4096, 256, 0, stream>>>(Wih_f, Whh_f, Wih_b, Whh_b, Wcat);
    k_bias<<<16, 256, 0, stream>>>(bih_f, bhh_f, bih_b, bhh_b, bias);
    k_zero<<<64, 256, 0, stream>>>(h_pub, flags);
    k_embed<<<8192, 256, 0, stream>>>(inputs, table, x);
    k_mask<<<128, 256, 0, stream>>>(lengths, out + OUT_MSK);
    lstm_recur<<<NWG, 256, 0, stream>>>(x, Wcat, h_pub, bias, lengths, out, flags);
}

// Round 6
// 4794.415 us; speedup vs baseline: 2.7587x; 1.0136x over previous
//
#include <hip/hip_runtime.h>

// ---------------------------------------------------------------------------
// TranslatorEncoderRNN: bidirectional masked LSTM encoder.
// B=64, T=512, E=512, H=512 (per dir), V=32000, PAD=0.
// Outputs (flat): output (B,T,1024) f32 | ht (B,1024) | ct (B,1024) | mask (B,T)
//
// R6: fix VGPR-spill hazard on inline-asm async loads (poll in batches of 8,
// gx in bf16) and shrink ws to 26.2 MB (< R2's proven envelope).
// Stamped-record h exchange kept (protocol proven lap-free).
// ---------------------------------------------------------------------------

#define Bn 64
#define Tn 512
#define NWG 64             // recurrent workgroups (32 per direction)
#define TC 32              // chunk length
#define NCH 16             // chunks

#define OUT_HT  33554432u  // B*T*2H
#define OUT_CT  33619968u
#define OUT_MSK 33685504u

// ws layout (bytes) — total 26,214,400
#define WS_WCAT 0ull           // Wcat bf16 [2][2048][1024]   =  8388608
#define WS_GXB  8388608ull     // gx  bf16 [2][32][64][2048]  = 16777216
#define WS_REC  25165824ull    // rec [2][2][8192]x16B        =   524288
#define WS_HST  25690112ull    // hstate f32 [2][64][512]     =   262144
#define WS_CST  25952256ull    // cstate f32 [2][64][512]     =   262144

typedef __bf16 v8bf __attribute__((ext_vector_type(8)));
typedef float  v4f  __attribute__((ext_vector_type(4)));
typedef unsigned v4u __attribute__((ext_vector_type(4)));
typedef unsigned v2u __attribute__((ext_vector_type(2)));

__device__ __forceinline__ unsigned short f2bf(float f) {
    unsigned u = __float_as_uint(f);
    u = (u + 0x7FFFu + ((u >> 16) & 1u)) >> 16;   // round-to-nearest-even
    return (unsigned short)u;
}

__device__ __forceinline__ void bf2x(unsigned u, float& lo, float& hi) {
    lo = __uint_as_float(u << 16);
    hi = __uint_as_float(u & 0xffff0000u);
}

__device__ __forceinline__ v8bf ldfrag(const unsigned short* p) {
    return *reinterpret_cast<const v8bf*>(p);
}

// coherent 16B load, ASYNC issue (must be drained with vmcnt(0)+sched_barrier
// before any register consumer; keep few in flight to avoid spills)
__device__ __forceinline__ v4u ld_co16(const void* p) {
    v4u r;
    asm volatile("global_load_dwordx4 %0, %1, off sc0 sc1" : "=v"(r) : "v"(p));
    return r;
}

// coherent 16B load, SYNC: waitcnt fused in the same asm block.
__device__ __forceinline__ v4u ld_co16_sync(const void* p) {
    v4u r;
    asm volatile("global_load_dwordx4 %0, %1, off sc0 sc1\n\ts_waitcnt vmcnt(0)"
                 : "=v"(r) : "v"(p) : "memory");
    return r;
}

__device__ __forceinline__ float fsig(float x) {
    return 1.0f / (1.0f + __expf(-x));
}
__device__ __forceinline__ float ftanh(float x) {
    x = fminf(fmaxf(x, -15.0f), 15.0f);
    float e = __expf(2.0f * x);
    return (e - 1.0f) / (e + 1.0f);
}

// --------------------------- prep kernels ----------------------------------

__global__ void k_weights(const float* __restrict__ Wih_f, const float* __restrict__ Whh_f,
                          const float* __restrict__ Wih_b, const float* __restrict__ Whh_b,
                          unsigned short* __restrict__ Wcat) {
    int idx = blockIdx.x * 256 + threadIdx.x;       // one per 4 elements
    if (idx >= 2 * 2048 * 256) return;
    int k4 = idx & 255;
    int n  = (idx >> 8) & 2047;
    int d  = idx >> 19;
    int k  = k4 * 4;
    const float* src;
    if (k < 512) src = (d ? Wih_b : Wih_f) + (size_t)n * 512 + k;
    else         src = (d ? Whh_b : Whh_f) + (size_t)n * 512 + (k - 512);
    float4 v = *(const float4*)src;
    unsigned short o[4] = { f2bf(v.x), f2bf(v.y), f2bf(v.z), f2bf(v.w) };
    *(ushort4*)(Wcat + (size_t)idx * 4) = *(const ushort4*)o;
}

// zero records (stamps) and h/c carry state
__global__ void k_zero(unsigned char* __restrict__ recb,
                       float* __restrict__ hstate, float* __restrict__ cstate) {
    int i = blockIdx.x * 256 + threadIdx.x;         // grid 256x256 = 65536
    if (i < 32768) { v4u z = {0,0,0,0}; ((v4u*)recb)[i] = z; }
    if (i < 65536) { hstate[i] = 0.0f; cstate[i] = 0.0f; }
}

__global__ void k_mask(const int* __restrict__ lengths, float* __restrict__ mask_out) {
    int i = blockIdx.x * 256 + threadIdx.x;
    if (i >= Bn * Tn) return;
    int b = i >> 9, t = i & 511;
    mask_out[i] = (t < lengths[b]) ? 1.0f : 0.0f;
}

// --------------------------- gx GEMM (per chunk) ----------------------------
// gxb[d][sl][b][n] = bf16( emb(inputs[b][t]) @ Wih_d^T + bih[n] + bhh[n] )
// Block (d, slg, nt): stage Wih 128-col tile once, reuse across 4 time steps.

__global__ __launch_bounds__(256) void k_gx(
    const int* __restrict__ inputs,
    const float* __restrict__ table,
    const unsigned short* __restrict__ Wcat,
    const float* __restrict__ bih_f, const float* __restrict__ bhh_f,
    const float* __restrict__ bih_b, const float* __restrict__ bhh_b,
    unsigned short* __restrict__ gxb, int s0)
{
    __shared__ unsigned short Bs[128 * 512];        // 128 KB
    const int bi   = blockIdx.x;                    // grid 256
    const int nt   = bi & 15;
    const int slg  = (bi >> 4) & 7;
    const int d    = bi >> 7;
    const int n0   = nt * 128;
    const int tid  = threadIdx.x;
    const int lane = tid & 63, wave = tid >> 6;
    const int l15  = lane & 15, kq = lane >> 4;

    const unsigned short* Wd = Wcat + (size_t)d * (2048 * 1024);

    // stage B tile (rows n0..n0+127, k 0..511) swizzled
    #pragma unroll
    for (int i = 0; i < 32; ++i) {
        int w = i * 256 + tid;
        int r = w >> 6, c = w & 63;
        v4u tmp = *(const v4u*)(Wd + (size_t)(n0 + r) * 1024 + c * 8);
        *(v4u*)&Bs[r * 512 + ((c ^ (r & 7)) * 8)] = tmp;
    }

    // bias for my output columns, n = n0 + n2*16 + l15
    const float* bih = d ? bih_b : bih_f;
    const float* bhh = d ? bhh_b : bhh_f;
    float bv[8];
    #pragma unroll
    for (int n2 = 0; n2 < 8; ++n2) {
        int n = n0 + n2 * 16 + l15;
        bv[n2] = bih[n] + bhh[n];
    }
    __syncthreads();

    const int ab   = wave * 16 + l15;               // batch row for A-frag
    const int brow = wave * 16 + kq * 4;            // C/D row base

    #pragma unroll 1
    for (int q = 0; q < 4; ++q) {
        const int sl = slg * 4 + q;
        const int s  = s0 + sl;
        const int t  = d ? (511 - s) : s;
        const int tok = inputs[ab * 512 + t];

        v8bf af[16];
        if (tok != 0) {
            const float* tr = table + (size_t)tok * 512 + kq * 8;
            #pragma unroll
            for (int ks = 0; ks < 16; ++ks) {
                float4 v0 = *(const float4*)(tr + ks * 32);
                float4 v1 = *(const float4*)(tr + ks * 32 + 4);
                unsigned short o[8] = { f2bf(v0.x), f2bf(v0.y), f2bf(v0.z), f2bf(v0.w),
                                        f2bf(v1.x), f2bf(v1.y), f2bf(v1.z), f2bf(v1.w) };
                af[ks] = *(const v8bf*)o;
            }
        } else {
            v4u z = {0u, 0u, 0u, 0u};
            #pragma unroll
            for (int ks = 0; ks < 16; ++ks) af[ks] = __builtin_bit_cast(v8bf, z);
        }

        unsigned short* gbase = gxb + ((size_t)(d * TC + sl) * 64) * 2048;
        #pragma unroll
        for (int n2 = 0; n2 < 8; ++n2) {
            v4f acc = {0, 0, 0, 0};
            const int rb = n2 * 16 + l15;
            const unsigned short* bbp = Bs + rb * 512;
            const int sw = rb & 7;
            #pragma unroll
            for (int ks = 0; ks < 16; ++ks) {
                v8bf bf = *(const v8bf*)&bbp[((ks * 4 + kq) ^ sw) * 8];
                acc = __builtin_amdgcn_mfma_f32_16x16x32_bf16(af[ks], bf, acc, 0, 0, 0);
            }
            const int n = n0 + n2 * 16 + l15;
            #pragma unroll
            for (int qq = 0; qq < 4; ++qq)
                gbase[(size_t)(brow + qq) * 2048 + n] = f2bf(acc[qq] + bv[n2]);
        }
    }
}

// --------------------------- recurrent kernel ------------------------------

__global__ __launch_bounds__(256, 1) void lstm_recur(
    const unsigned short* __restrict__ Wcat,
    unsigned char* __restrict__ recb,           // [2][2][8192] x 16B
    const unsigned short* __restrict__ gxb,     // [2][TC][64][2048] bf16
    const int* __restrict__ lengths,
    float* __restrict__ out,
    float* __restrict__ hstate,
    float* __restrict__ cstate,
    int s0)
{
    const int wg   = blockIdx.x;
    const int dir  = wg >> 5;
    const int hc0  = (wg & 31) * 16;
    const int tid  = threadIdx.x;
    const int lane = tid & 63;
    const int wave = tid >> 6;
    const int wm   = wave >> 1, wn = wave & 1;
    const int l15  = lane & 15, kq = lane >> 4;
    const int eb   = tid >> 2, ejg = tid & 3;

    __shared__ unsigned short hA[64 * 512];     // 64 KB swizzled h tile
    __shared__ float gLds[64][65];
    __shared__ float hS[64][17];
    __shared__ float cS[64][17];
    __shared__ int   lenS[64];

    // load carry state
    {
        const size_t so = (size_t)dir * (64 * 512) + (size_t)eb * 512 + hc0 + ejg * 4;
        v4f hv = *(const v4f*)(hstate + so);
        v4f cv = *(const v4f*)(cstate + so);
        #pragma unroll
        for (int jj = 0; jj < 4; ++jj) { hS[eb][ejg * 4 + jj] = hv[jj]; cS[eb][ejg * 4 + jj] = cv[jj]; }
        if (tid < 64) lenS[tid] = lengths[tid];
    }

    const unsigned short* Wd = Wcat + (size_t)dir * (2048 * 1024);
    const int rowA0 = 32 * wm + l15, rowA1 = rowA0 + 16;
    const int n0 = (2 * wn + 0) * 512 + hc0 + l15;
    const int n1 = (2 * wn + 1) * 512 + hc0 + l15;
    const unsigned short* pB0 = Wd + (size_t)n0 * 1024 + kq * 8;
    const unsigned short* pB1 = Wd + (size_t)n1 * 1024 + kq * 8;

    // Whh fragments in registers (K = 512..1023): 128 VGPRs
    v8bf whB0[16], whB1[16];
    #pragma unroll
    for (int ks = 0; ks < 16; ++ks) {
        whB0[ks] = ldfrag(pB0 + (16 + ks) * 32);
        whB1[ks] = ldfrag(pB1 + (16 + ks) * 32);
    }

    const unsigned short* lA0 = hA + rowA0 * 512;
    const unsigned short* lA1 = hA + rowA1 * 512;
    const int swA0 = (rowA0 & 7) << 3, swA1 = (rowA1 & 7) << 3;

    unsigned char* recD = recb + (size_t)dir * 262144;   // 2 phases x 131072

    __syncthreads();

    for (int sl = 0; sl < TC; ++sl) {
        const int s = s0 + sl;
        const int t = dir ? (511 - s) : s;
        const unsigned want = (unsigned)s;

        // gx prefetch (bf16, 8 VGPRs) — plain loads, compiler-managed waits
        v2u gw0, gw1, gw2, gw3;
        {
            const unsigned short* g = gxb + ((size_t)(dir * TC + sl) * 64 + eb) * 2048 + hc0 + ejg * 4;
            gw0 = *(const v2u*)(g);
            gw1 = *(const v2u*)(g + 512);
            gw2 = *(const v2u*)(g + 1024);
            gw3 = *(const v2u*)(g + 1536);
        }

        // poll stamped records for step s in batches of 8 (32 live VGPRs max,
        // no spill window between asm def and vmcnt drain)
        unsigned char* rp = recD + (size_t)(s & 1) * 131072;
        #pragma unroll
        for (int grp = 0; grp < 4; ++grp) {
            v4u r[8];
            #pragma unroll
            for (int i = 0; i < 8; ++i)
                r[i] = ld_co16(rp + (size_t)((grp * 8 + i) * 256 + tid) * 16);
            asm volatile("s_waitcnt vmcnt(0)" ::: "memory");
            __builtin_amdgcn_sched_barrier(0);      // rule #18 fence
            #pragma unroll
            for (int i = 0; i < 8; ++i) {
                int idx = (grp * 8 + i) * 256 + tid;
                while (r[i][3] != want) {
                    r[i] = ld_co16_sync(rp + (size_t)idx * 16);
                }
                int b = idx >> 7, j4 = idx & 127;
                v2u hv = { r[i][0], r[i][1] };
                *(v2u*)&hA[b * 512 + ((j4 * 4) ^ ((b & 7) << 3))] = hv;
            }
        }
        __syncthreads();

        // h-GEMM: K = 512, A from LDS, B from registers
        v4f a00 = {0,0,0,0}, a01 = {0,0,0,0}, a10 = {0,0,0,0}, a11 = {0,0,0,0};
        #pragma unroll
        for (int ks = 0; ks < 16; ++ks) {
            v8bf fa0 = *(const v8bf*)&lA0[(kq * 8 + ks * 32) ^ swA0];
            v8bf fa1 = *(const v8bf*)&lA1[(kq * 8 + ks * 32) ^ swA1];
            a00 = __builtin_amdgcn_mfma_f32_16x16x32_bf16(fa0, whB0[ks], a00, 0, 0, 0);
            a01 = __builtin_amdgcn_mfma_f32_16x16x32_bf16(fa0, whB1[ks], a01, 0, 0, 0);
            a10 = __builtin_amdgcn_mfma_f32_16x16x32_bf16(fa1, whB0[ks], a10, 0, 0, 0);
            a11 = __builtin_amdgcn_mfma_f32_16x16x32_bf16(fa1, whB1[ks], a11, 0, 0, 0);
        }

        // gates -> LDS. C/D: col = lane&15, row = (lane>>4)*4 + reg.
        {
            int c0 = 32 * wn + l15;
            int rr = 32 * wm + kq * 4;
            #pragma unroll
            for (int q = 0; q < 4; ++q) {
                gLds[rr + q][c0     ] = a00[q];
                gLds[rr + q][c0 + 16] = a01[q];
                gLds[rr + 16 + q][c0     ] = a10[q];
                gLds[rr + 16 + q][c0 + 16] = a11[q];
            }
        }
        __syncthreads();

        // elementwise LSTM: thread (b = tid>>2, cols hc0 + (tid&3)*4 + 0..3)
        {
            const int b = eb, jg = ejg;
            const int msk = (t < lenS[b]);
            float gxi[4], gxf[4], gxg[4], gxo[4];
            bf2x(gw0[0], gxi[0], gxi[1]); bf2x(gw0[1], gxi[2], gxi[3]);
            bf2x(gw1[0], gxf[0], gxf[1]); bf2x(gw1[1], gxf[2], gxf[3]);
            bf2x(gw2[0], gxg[0], gxg[1]); bf2x(gw2[1], gxg[2], gxg[3]);
            bf2x(gw3[0], gxo[0], gxo[1]); bf2x(gw3[1], gxo[2], gxo[3]);
            float hn[4], cn[4];
            #pragma unroll
            for (int jj = 0; jj < 4; ++jj) {
                int j = jg * 4 + jj;
                float gi = gLds[b][j]      + gxi[jj];
                float gf = gLds[b][16 + j] + gxf[jj];
                float gg = gLds[b][32 + j] + gxg[jj];
                float go = gLds[b][48 + j] + gxo[jj];
                float i_ = fsig(gi), f_ = fsig(gf), o_ = fsig(go), g_ = ftanh(gg);
                float c_old = cS[b][j], h_old = hS[b][j];
                float c_new = fmaf(f_, c_old, i_ * g_);
                float h_new = o_ * ftanh(c_new);
                if (!msk) { c_new = c_old; h_new = h_old; }
                cS[b][j] = c_new;
                hS[b][j] = h_new;
                hn[jj] = h_new; cn[jj] = c_new;
            }
            // publish first (single fire-and-forget coherent 16B record)
            if (s < 511) {
                unsigned short q0 = f2bf(hn[0]), q1 = f2bf(hn[1]), q2 = f2bf(hn[2]), q3 = f2bf(hn[3]);
                v4u pk = { (unsigned)q0 | ((unsigned)q1 << 16),
                           (unsigned)q2 | ((unsigned)q3 << 16),
                           0u, (unsigned)(s + 1) };
                int idxp = b * 128 + (wg & 31) * 4 + jg;
                unsigned char* dst = recD + (size_t)((s + 1) & 1) * 131072 + (size_t)idxp * 16;
                asm volatile("global_store_dwordx4 %0, %1, off sc0 sc1" :: "v"(dst), "v"(pk) : "memory");
            }
            v4f ov = {hn[0], hn[1], hn[2], hn[3]};
            *(v4f*)&out[((size_t)b * 512 + t) * 1024 + (size_t)dir * 512 + hc0 + jg * 4] = ov;
            if (s == 511) {
                v4f cv2 = {cn[0], cn[1], cn[2], cn[3]};
                *(v4f*)&out[OUT_HT + (size_t)b * 1024 + dir * 512 + hc0 + jg * 4] = ov;
                *(v4f*)&out[OUT_CT + (size_t)b * 1024 + dir * 512 + hc0 + jg * 4] = cv2;
            }
        }
        __syncthreads();   // protect gLds/hA reuse next step
    }

    // save carry state
    {
        float hv[4], cv[4];
        #pragma unroll
        for (int jj = 0; jj < 4; ++jj) { hv[jj] = hS[eb][ejg * 4 + jj]; cv[jj] = cS[eb][ejg * 4 + jj]; }
        const size_t so = (size_t)dir * (64 * 512) + (size_t)eb * 512 + hc0 + ejg * 4;
        *(v4f*)(hstate + so) = *(v4f*)hv;
        *(v4f*)(cstate + so) = *(v4f*)cv;
    }
}

// --------------------------- launcher --------------------------------------

extern "C" void kernel_launch(void* const* d_in, const int* in_sizes, int n_in,
                              void* d_out, int out_size, void* d_ws, size_t ws_size,
                              hipStream_t stream) {
    (void)in_sizes; (void)n_in; (void)out_size; (void)ws_size;

    const int*   inputs  = (const int*)d_in[0];
    const int*   lengths = (const int*)d_in[1];
    const float* table   = (const float*)d_in[2];
    const float* Wih_f   = (const float*)d_in[3];
    const float* Whh_f   = (const float*)d_in[4];
    const float* bih_f   = (const float*)d_in[5];
    const float* bhh_f   = (const float*)d_in[6];
    const float* Wih_b   = (const float*)d_in[7];
    const float* Whh_b   = (const float*)d_in[8];
    const float* bih_b   = (const float*)d_in[9];
    const float* bhh_b   = (const float*)d_in[10];
    float* out = (float*)d_out;

    char* w = (char*)d_ws;
    unsigned short* Wcat   = (unsigned short*)(w + WS_WCAT);
    unsigned short* gxb    = (unsigned short*)(w + WS_GXB);
    unsigned char*  recb   = (unsigned char*)(w + WS_REC);
    float*          hstate = (float*)(w + WS_HST);
    float*          cstate = (float*)(w + WS_CST);

    k_weights<<<4096, 256, 0, stream>>>(Wih_f, Whh_f, Wih_b, Whh_b, Wcat);
    k_zero<<<256, 256, 0, stream>>>(recb, hstate, cstate);
    k_mask<<<128, 256, 0, stream>>>(lengths, out + OUT_MSK);

    for (int ch = 0; ch < NCH; ++ch) {
        k_gx<<<256, 256, 0, stream>>>(inputs, table, Wcat,
                                      bih_f, bhh_f, bih_b, bhh_b, gxb, ch * TC);
        lstm_recur<<<NWG, 256, 0, stream>>>(Wcat, recb, gxb, lengths, out,
                                            hstate, cstate, ch * TC);
    }
}

// Round 11
// 4261.629 us; speedup vs baseline: 3.1036x; 1.1250x over previous
//
#include <hip/hip_runtime.h>

// ---------------------------------------------------------------------------
// TranslatorEncoderRNN: bidirectional masked LSTM encoder.
// B=64, T=512, E=512, H=512 (per dir), V=32000, PAD=0.
// Outputs (flat): output (B,T,1024) f32 | ht (B,1024) | ct (B,1024) | mask (B,T)
//
// R11: EXACT R6 base (the only proven-green structure) + two scoped edits:
//  (1) poll retry = wave-uniform bulk reload (pattern (a) body inside
//      while(__any)): unconditional 8x ld_co16 + drain + sched_barrier.
//  (2) k_gx blockIdx permutation for XCD locality of the embedding gather.
// ASM-LOAD RULES (empirical R3-R10):
//   (a) unconditional batch of <=8 ld_co16 + vmcnt(0) + sched_barrier(0); or
//   (b) fused {load; waitcnt} single asm block.
//   NEVER >8 live asm loads (1.1118 spill signature).
//   NEVER issue asm loads under divergent branches (NaN signature).
//   NO separate producer-split kernels feeding gxb (R8/R9/R10 NaN — cause
//   unresolved; monolithic k_gx is proven).
// ---------------------------------------------------------------------------

#define Bn 64
#define Tn 512
#define NWG 64             // recurrent workgroups (32 per direction)
#define TC 32              // chunk length
#define NCH 16             // chunks

#define OUT_HT  33554432u  // B*T*2H
#define OUT_CT  33619968u
#define OUT_MSK 33685504u

// ws layout (bytes) — total 26,214,400 (EXACT R6)
#define WS_WCAT 0ull           // Wcat bf16 [2][2048][1024]   =  8388608
#define WS_GXB  8388608ull     // gx  bf16 [2][32][64][2048]  = 16777216
#define WS_REC  25165824ull    // rec [2][2][8192]x16B        =   524288
#define WS_HST  25690112ull    // hstate f32 [2][64][512]     =   262144
#define WS_CST  25952256ull    // cstate f32 [2][64][512]     =   262144

typedef __bf16 v8bf __attribute__((ext_vector_type(8)));
typedef float  v4f  __attribute__((ext_vector_type(4)));
typedef unsigned v4u __attribute__((ext_vector_type(4)));
typedef unsigned v2u __attribute__((ext_vector_type(2)));

__device__ __forceinline__ unsigned short f2bf(float f) {
    unsigned u = __float_as_uint(f);
    u = (u + 0x7FFFu + ((u >> 16) & 1u)) >> 16;   // round-to-nearest-even
    return (unsigned short)u;
}

__device__ __forceinline__ void bf2x(unsigned u, float& lo, float& hi) {
    lo = __uint_as_float(u << 16);
    hi = __uint_as_float(u & 0xffff0000u);
}

__device__ __forceinline__ v8bf ldfrag(const unsigned short* p) {
    return *reinterpret_cast<const v8bf*>(p);
}

// coherent 16B load, ASYNC issue — pattern (a) only
__device__ __forceinline__ v4u ld_co16(const void* p) {
    v4u r;
    asm volatile("global_load_dwordx4 %0, %1, off sc0 sc1" : "=v"(r) : "v"(p));
    return r;
}

__device__ __forceinline__ float fsig(float x) {
    return 1.0f / (1.0f + __expf(-x));
}
__device__ __forceinline__ float ftanh(float x) {
    x = fminf(fmaxf(x, -15.0f), 15.0f);
    float e = __expf(2.0f * x);
    return (e - 1.0f) / (e + 1.0f);
}

// --------------------------- prep kernels ----------------------------------

__global__ void k_weights(const float* __restrict__ Wih_f, const float* __restrict__ Whh_f,
                          const float* __restrict__ Wih_b, const float* __restrict__ Whh_b,
                          unsigned short* __restrict__ Wcat) {
    int idx = blockIdx.x * 256 + threadIdx.x;       // one per 4 elements
    if (idx >= 2 * 2048 * 256) return;
    int k4 = idx & 255;
    int n  = (idx >> 8) & 2047;
    int d  = idx >> 19;
    int k  = k4 * 4;
    const float* src;
    if (k < 512) src = (d ? Wih_b : Wih_f) + (size_t)n * 512 + k;
    else         src = (d ? Whh_b : Whh_f) + (size_t)n * 512 + (k - 512);
    float4 v = *(const float4*)src;
    unsigned short o[4] = { f2bf(v.x), f2bf(v.y), f2bf(v.z), f2bf(v.w) };
    *(ushort4*)(Wcat + (size_t)idx * 4) = *(const ushort4*)o;
}

// zero records (stamps) and h/c carry state
__global__ void k_zero(unsigned char* __restrict__ recb,
                       float* __restrict__ hstate, float* __restrict__ cstate) {
    int i = blockIdx.x * 256 + threadIdx.x;         // grid 256x256 = 65536
    if (i < 32768) { v4u z = {0,0,0,0}; ((v4u*)recb)[i] = z; }
    if (i < 65536) { hstate[i] = 0.0f; cstate[i] = 0.0f; }
}

__global__ void k_mask(const int* __restrict__ lengths, float* __restrict__ mask_out) {
    int i = blockIdx.x * 256 + threadIdx.x;
    if (i >= Bn * Tn) return;
    int b = i >> 9, t = i & 511;
    mask_out[i] = (t < lengths[b]) ? 1.0f : 0.0f;
}

// --------------------------- gx GEMM (per chunk) ----------------------------
// gxb[d][sl][b][n] = bf16( emb(inputs[b][t]) @ Wih_d^T + bih[n] + bhh[n] )
// Block (d, slg, nt): stage Wih 128-col tile once, reuse across 4 time steps.
// blockIdx permuted so all 16 nt-blocks of one (d,slg) share an XCD (mod 8):
// their duplicated embedding gathers then hit the same L2.

__global__ __launch_bounds__(256) void k_gx(
    const int* __restrict__ inputs,
    const float* __restrict__ table,
    const unsigned short* __restrict__ Wcat,
    const float* __restrict__ bih_f, const float* __restrict__ bhh_f,
    const float* __restrict__ bih_b, const float* __restrict__ bhh_b,
    unsigned short* __restrict__ gxb, int s0)
{
    __shared__ unsigned short Bs[128 * 512];        // 128 KB
    const int bi   = blockIdx.x;                    // grid 256
    const int nt   = bi >> 4;                       // stride-16 -> same XCD for fixed (d,slg)
    const int d    = (bi >> 3) & 1;
    const int slg  = bi & 7;
    const int n0   = nt * 128;
    const int tid  = threadIdx.x;
    const int lane = tid & 63, wave = tid >> 6;
    const int l15  = lane & 15, kq = lane >> 4;

    const unsigned short* Wd = Wcat + (size_t)d * (2048 * 1024);

    // stage B tile (rows n0..n0+127, k 0..511) swizzled
    #pragma unroll
    for (int i = 0; i < 32; ++i) {
        int w = i * 256 + tid;
        int r = w >> 6, c = w & 63;
        v4u tmp = *(const v4u*)(Wd + (size_t)(n0 + r) * 1024 + c * 8);
        *(v4u*)&Bs[r * 512 + ((c ^ (r & 7)) * 8)] = tmp;
    }

    const float* bih = d ? bih_b : bih_f;
    const float* bhh = d ? bhh_b : bhh_f;
    float bv[8];
    #pragma unroll
    for (int n2 = 0; n2 < 8; ++n2) {
        int n = n0 + n2 * 16 + l15;
        bv[n2] = bih[n] + bhh[n];
    }
    __syncthreads();

    const int ab   = wave * 16 + l15;               // batch row for A-frag
    const int brow = wave * 16 + kq * 4;            // C/D row base

    #pragma unroll 1
    for (int q = 0; q < 4; ++q) {
        const int sl = slg * 4 + q;
        const int s  = s0 + sl;
        const int t  = d ? (511 - s) : s;
        const int tok = inputs[ab * 512 + t];

        v8bf af[16];
        if (tok != 0) {
            const float* tr = table + (size_t)tok * 512 + kq * 8;
            #pragma unroll
            for (int ks = 0; ks < 16; ++ks) {
                float4 v0 = *(const float4*)(tr + ks * 32);
                float4 v1 = *(const float4*)(tr + ks * 32 + 4);
                unsigned short o[8] = { f2bf(v0.x), f2bf(v0.y), f2bf(v0.z), f2bf(v0.w),
                                        f2bf(v1.x), f2bf(v1.y), f2bf(v1.z), f2bf(v1.w) };
                af[ks] = *(const v8bf*)o;
            }
        } else {
            v4u z = {0u, 0u, 0u, 0u};
            #pragma unroll
            for (int ks = 0; ks < 16; ++ks) af[ks] = __builtin_bit_cast(v8bf, z);
        }

        unsigned short* gbase = gxb + ((size_t)(d * TC + sl) * 64) * 2048;
        #pragma unroll
        for (int n2 = 0; n2 < 8; ++n2) {
            v4f acc = {0, 0, 0, 0};
            const int rb = n2 * 16 + l15;
            const unsigned short* bbp = Bs + rb * 512;
            const int sw = rb & 7;
            #pragma unroll
            for (int ks = 0; ks < 16; ++ks) {
                v8bf bf = *(const v8bf*)&bbp[((ks * 4 + kq) ^ sw) * 8];
                acc = __builtin_amdgcn_mfma_f32_16x16x32_bf16(af[ks], bf, acc, 0, 0, 0);
            }
            const int n = n0 + n2 * 16 + l15;
            #pragma unroll
            for (int qq = 0; qq < 4; ++qq)
                gbase[(size_t)(brow + qq) * 2048 + n] = f2bf(acc[qq] + bv[n2]);
        }
    }
}

// --------------------------- recurrent kernel ------------------------------

__global__ __launch_bounds__(256, 1) void lstm_recur(
    const unsigned short* __restrict__ Wcat,
    unsigned char* __restrict__ recb,           // [2][2][8192] x 16B
    const unsigned short* __restrict__ gxb,     // [2][TC][64][2048] bf16
    const int* __restrict__ lengths,
    float* __restrict__ out,
    float* __restrict__ hstate,
    float* __restrict__ cstate,
    int s0)
{
    const int wg   = blockIdx.x;
    const int dir  = wg >> 5;
    const int hc0  = (wg & 31) * 16;
    const int tid  = threadIdx.x;
    const int lane = tid & 63;
    const int wave = tid >> 6;
    const int wm   = wave >> 1, wn = wave & 1;
    const int l15  = lane & 15, kq = lane >> 4;
    const int eb   = tid >> 2, ejg = tid & 3;

    __shared__ unsigned short hA[64 * 512];     // 64 KB swizzled h tile
    __shared__ float gLds[64][65];
    __shared__ float hS[64][17];
    __shared__ float cS[64][17];
    __shared__ int   lenS[64];

    // load carry state
    {
        const size_t so = (size_t)dir * (64 * 512) + (size_t)eb * 512 + hc0 + ejg * 4;
        v4f hv = *(const v4f*)(hstate + so);
        v4f cv = *(const v4f*)(cstate + so);
        #pragma unroll
        for (int jj = 0; jj < 4; ++jj) { hS[eb][ejg * 4 + jj] = hv[jj]; cS[eb][ejg * 4 + jj] = cv[jj]; }
        if (tid < 64) lenS[tid] = lengths[tid];
    }

    const unsigned short* Wd = Wcat + (size_t)dir * (2048 * 1024);
    const int rowA0 = 32 * wm + l15, rowA1 = rowA0 + 16;
    const int n0 = (2 * wn + 0) * 512 + hc0 + l15;
    const int n1 = (2 * wn + 1) * 512 + hc0 + l15;
    const unsigned short* pB0 = Wd + (size_t)n0 * 1024 + kq * 8;
    const unsigned short* pB1 = Wd + (size_t)n1 * 1024 + kq * 8;

    // Whh fragments in registers (K = 512..1023): 128 VGPRs
    v8bf whB0[16], whB1[16];
    #pragma unroll
    for (int ks = 0; ks < 16; ++ks) {
        whB0[ks] = ldfrag(pB0 + (16 + ks) * 32);
        whB1[ks] = ldfrag(pB1 + (16 + ks) * 32);
    }

    const unsigned short* lA0 = hA + rowA0 * 512;
    const unsigned short* lA1 = hA + rowA1 * 512;
    const int swA0 = (rowA0 & 7) << 3, swA1 = (rowA1 & 7) << 3;

    unsigned char* recD = recb + (size_t)dir * 262144;   // 2 phases x 131072

    __syncthreads();

    for (int sl = 0; sl < TC; ++sl) {
        const int s = s0 + sl;
        const int t = dir ? (511 - s) : s;
        const unsigned want = (unsigned)s;

        // gx prefetch (bf16, 8 VGPRs) — plain loads, compiler-managed waits
        v2u gw0, gw1, gw2, gw3;
        {
            const unsigned short* g = gxb + ((size_t)(dir * TC + sl) * 64 + eb) * 2048 + hc0 + ejg * 4;
            gw0 = *(const v2u*)(g);
            gw1 = *(const v2u*)(g + 512);
            gw2 = *(const v2u*)(g + 1024);
            gw3 = *(const v2u*)(g + 1536);
        }

        // poll stamped records for step s in batches of 8 (HARD LIMIT 8);
        // retries are wave-uniform bulk reloads (pattern (a) body).
        unsigned char* rp = recD + (size_t)(s & 1) * 131072;
        #pragma unroll
        for (int grp = 0; grp < 4; ++grp) {
            v4u r[8];
            #pragma unroll
            for (int i = 0; i < 8; ++i)
                r[i] = ld_co16(rp + (size_t)((grp * 8 + i) * 256 + tid) * 16);
            asm volatile("s_waitcnt vmcnt(0)" ::: "memory");
            __builtin_amdgcn_sched_barrier(0);      // rule #18 fence
            unsigned stale = 0u;
            #pragma unroll
            for (int i = 0; i < 8; ++i) {
                int idx = (grp * 8 + i) * 256 + tid;
                if (r[i][3] == want) {
                    int b = idx >> 7, j4 = idx & 127;
                    v2u hv = { r[i][0], r[i][1] };
                    *(v2u*)&hA[b * 512 + ((j4 * 4) ^ ((b & 7) << 3))] = hv;
                } else {
                    stale |= (1u << i);
                }
            }
            while (__any(stale != 0u)) {            // wave-uniform
                v4u q[8];
                #pragma unroll
                for (int i = 0; i < 8; ++i)         // UNCONDITIONAL reload
                    q[i] = ld_co16(rp + (size_t)((grp * 8 + i) * 256 + tid) * 16);
                asm volatile("s_waitcnt vmcnt(0)" ::: "memory");
                __builtin_amdgcn_sched_barrier(0);  // rule #18 fence
                #pragma unroll
                for (int i = 0; i < 8; ++i) {
                    if ((stale & (1u << i)) && q[i][3] == want) {
                        int idx = (grp * 8 + i) * 256 + tid;
                        int b = idx >> 7, j4 = idx & 127;
                        v2u hv = { q[i][0], q[i][1] };
                        *(v2u*)&hA[b * 512 + ((j4 * 4) ^ ((b & 7) << 3))] = hv;
                        stale &= ~(1u << i);
                    }
                }
            }
        }
        __syncthreads();

        // h-GEMM: K = 512, A from LDS, B from registers
        v4f a00 = {0,0,0,0}, a01 = {0,0,0,0}, a10 = {0,0,0,0}, a11 = {0,0,0,0};
        #pragma unroll
        for (int ks = 0; ks < 16; ++ks) {
            v8bf fa0 = *(const v8bf*)&lA0[(kq * 8 + ks * 32) ^ swA0];
            v8bf fa1 = *(const v8bf*)&lA1[(kq * 8 + ks * 32) ^ swA1];
            a00 = __builtin_amdgcn_mfma_f32_16x16x32_bf16(fa0, whB0[ks], a00, 0, 0, 0);
            a01 = __builtin_amdgcn_mfma_f32_16x16x32_bf16(fa0, whB1[ks], a01, 0, 0, 0);
            a10 = __builtin_amdgcn_mfma_f32_16x16x32_bf16(fa1, whB0[ks], a10, 0, 0, 0);
            a11 = __builtin_amdgcn_mfma_f32_16x16x32_bf16(fa1, whB1[ks], a11, 0, 0, 0);
        }

        // gates -> LDS. C/D: col = lane&15, row = (lane>>4)*4 + reg.
        {
            int c0 = 32 * wn + l15;
            int rr = 32 * wm + kq * 4;
            #pragma unroll
            for (int q = 0; q < 4; ++q) {
                gLds[rr + q][c0     ] = a00[q];
                gLds[rr + q][c0 + 16] = a01[q];
                gLds[rr + 16 + q][c0     ] = a10[q];
                gLds[rr + 16 + q][c0 + 16] = a11[q];
            }
        }
        __syncthreads();

        // elementwise LSTM: thread (b = tid>>2, cols hc0 + (tid&3)*4 + 0..3)
        {
            const int b = eb, jg = ejg;
            const int msk = (t < lenS[b]);
            float gxi[4], gxf[4], gxg[4], gxo[4];
            bf2x(gw0[0], gxi[0], gxi[1]); bf2x(gw0[1], gxi[2], gxi[3]);
            bf2x(gw1[0], gxf[0], gxf[1]); bf2x(gw1[1], gxf[2], gxf[3]);
            bf2x(gw2[0], gxg[0], gxg[1]); bf2x(gw2[1], gxg[2], gxg[3]);
            bf2x(gw3[0], gxo[0], gxo[1]); bf2x(gw3[1], gxo[2], gxo[3]);
            float hn[4], cn[4];
            #pragma unroll
            for (int jj = 0; jj < 4; ++jj) {
                int j = jg * 4 + jj;
                float gi = gLds[b][j]      + gxi[jj];
                float gf = gLds[b][16 + j] + gxf[jj];
                float gg = gLds[b][32 + j] + gxg[jj];
                float go = gLds[b][48 + j] + gxo[jj];
                float i_ = fsig(gi), f_ = fsig(gf), o_ = fsig(go), g_ = ftanh(gg);
                float c_old = cS[b][j], h_old = hS[b][j];
                float c_new = fmaf(f_, c_old, i_ * g_);
                float h_new = o_ * ftanh(c_new);
                if (!msk) { c_new = c_old; h_new = h_old; }
                cS[b][j] = c_new;
                hS[b][j] = h_new;
                hn[jj] = h_new; cn[jj] = c_new;
            }
            // publish first (single fire-and-forget coherent 16B record)
            if (s < 511) {
                unsigned short q0 = f2bf(hn[0]), q1 = f2bf(hn[1]), q2 = f2bf(hn[2]), q3 = f2bf(hn[3]);
                v4u pk = { (unsigned)q0 | ((unsigned)q1 << 16),
                           (unsigned)q2 | ((unsigned)q3 << 16),
                           0u, (unsigned)(s + 1) };
                int idxp = b * 128 + (wg & 31) * 4 + jg;
                unsigned char* dst = recD + (size_t)((s + 1) & 1) * 131072 + (size_t)idxp * 16;
                asm volatile("global_store_dwordx4 %0, %1, off sc0 sc1" :: "v"(dst), "v"(pk) : "memory");
            }
            v4f ov = {hn[0], hn[1], hn[2], hn[3]};
            *(v4f*)&out[((size_t)b * 512 + t) * 1024 + (size_t)dir * 512 + hc0 + jg * 4] = ov;
            if (s == 511) {
                v4f cv2 = {cn[0], cn[1], cn[2], cn[3]};
                *(v4f*)&out[OUT_HT + (size_t)b * 1024 + dir * 512 + hc0 + jg * 4] = ov;
                *(v4f*)&out[OUT_CT + (size_t)b * 1024 + dir * 512 + hc0 + jg * 4] = cv2;
            }
        }
        __syncthreads();   // protect gLds/hA reuse next step
    }

    // save carry state
    {
        float hv[4], cv[4];
        #pragma unroll
        for (int jj = 0; jj < 4; ++jj) { hv[jj] = hS[eb][ejg * 4 + jj]; cv[jj] = cS[eb][ejg * 4 + jj]; }
        const size_t so = (size_t)dir * (64 * 512) + (size_t)eb * 512 + hc0 + ejg * 4;
        *(v4f*)(hstate + so) = *(v4f*)hv;
        *(v4f*)(cstate + so) = *(v4f*)cv;
    }
}

// --------------------------- launcher --------------------------------------

extern "C" void kernel_launch(void* const* d_in, const int* in_sizes, int n_in,
                              void* d_out, int out_size, void* d_ws, size_t ws_size,
                              hipStream_t stream) {
    (void)in_sizes; (void)n_in; (void)out_size; (void)ws_size;

    const int*   inputs  = (const int*)d_in[0];
    const int*   lengths = (const int*)d_in[1];
    const float* table   = (const float*)d_in[2];
    const float* Wih_f   = (const float*)d_in[3];
    const float* Whh_f   = (const float*)d_in[4];
    const float* bih_f   = (const float*)d_in[5];
    const float* bhh_f   = (const float*)d_in[6];
    const float* Wih_b   = (const float*)d_in[7];
    const float* Whh_b   = (const float*)d_in[8];
    const float* bih_b   = (const float*)d_in[9];
    const float* bhh_b   = (const float*)d_in[10];
    float* out = (float*)d_out;

    char* w = (char*)d_ws;
    unsigned short* Wcat   = (unsigned short*)(w + WS_WCAT);
    unsigned short* gxb    = (unsigned short*)(w + WS_GXB);
    unsigned char*  recb   = (unsigned char*)(w + WS_REC);
    float*          hstate = (float*)(w + WS_HST);
    float*          cstate = (float*)(w + WS_CST);

    k_weights<<<4096, 256, 0, stream>>>(Wih_f, Whh_f, Wih_b, Whh_b, Wcat);
    k_zero<<<256, 256, 0, stream>>>(recb, hstate, cstate);
    k_mask<<<128, 256, 0, stream>>>(lengths, out + OUT_MSK);

    for (int ch = 0; ch < NCH; ++ch) {
        k_gx<<<256, 256, 0, stream>>>(inputs, table, Wcat,
                                      bih_f, bhh_f, bih_b, bhh_b, gxb, ch * TC);
        lstm_recur<<<NWG, 256, 0, stream>>>(Wcat, recb, gxb, lengths, out,
                                            hstate, cstate, ch * TC);
    }
}